// Round 13
// baseline (875.247 us; speedup 1.0000x reference)
//
#include <hip/hip_runtime.h>
#include <hip/hip_bf16.h>

#define NTOK 49
#define NB 2048
#define SCALE 0.17677669529663687f  // 32^-0.5

typedef __attribute__((ext_vector_type(8))) short short8;
typedef __attribute__((ext_vector_type(4))) float f32x4;
typedef __attribute__((ext_vector_type(16))) float f32x16;
typedef __attribute__((ext_vector_type(4))) unsigned short u16x4;

#define MFMA32(a, b, c) __builtin_amdgcn_mfma_f32_32x32x16_bf16(a, b, c, 0, 0, 0)

static __device__ __forceinline__ unsigned short f2bf(float f) {
    union { float f; unsigned int u; } v; v.f = f;
    unsigned int r = v.u + 0x7FFFu + ((v.u >> 16) & 1u);
    return (unsigned short)(r >> 16);
}

static __device__ __forceinline__ unsigned int pkbf(float lo, float hi) {
    __hip_bfloat162 h = __float22bfloat162_rn(make_float2(lo, hi));  // .x -> low16
    union { __hip_bfloat162 h; unsigned int u; } c; c.h = h; return c.u;
}

// C/D tile (32x32, f32x16: col=lane&31, row=(r&3)+8*(r>>2)+4*hl) -> A/B frag
// k-block H2 (frag elem (l,j): tile[row = 16*H2 + 8*hl + j][col = l&31]).
// Needed rows: j0-3 from quad 2*H2 (hl=0 own / hl=1 partner-B ...), derivation:
//   dest hl=0 uses quad 2H2 (own j0-3, partner's for j4-7? no -- see mapping):
//   hl=0: j0-3 = own quad 2H2, j4-7 = partner quad 2H2
//   hl=1: j0-3 = partner quad 2H2+1, j4-7 = own quad 2H2+1
// Source sends the quad its partner needs (depends only on source half) ->
// pre-select + 2x shfl_xor(32). All VALU + 2 cross-lane ops (vs 8 bpermute).
template<int H2>
static __device__ __forceinline__ short8 fragcd(const f32x16 t, int hl) {
    unsigned int A0 = pkbf(t[8 * H2 + 0], t[8 * H2 + 1]);
    unsigned int A1 = pkbf(t[8 * H2 + 2], t[8 * H2 + 3]);
    unsigned int B0 = pkbf(t[8 * H2 + 4], t[8 * H2 + 5]);
    unsigned int B1 = pkbf(t[8 * H2 + 6], t[8 * H2 + 7]);
    unsigned int own0 = hl ? B0 : A0, own1 = hl ? B1 : A1;
    unsigned int snd0 = hl ? A0 : B0, snd1 = hl ? A1 : B1;
    unsigned int sw0 = (unsigned int)__shfl_xor((int)snd0, 32);
    unsigned int sw1 = (unsigned int)__shfl_xor((int)snd1, 32);
    union { short8 s; unsigned int u[4]; } r;
    r.u[0] = hl ? sw0 : own0;
    r.u[1] = hl ? sw1 : own1;
    r.u[2] = hl ? own0 : sw0;
    r.u[3] = hl ? own1 : sw1;
    return r.s;
}

// ---- workspace layout (bytes) ----
#define MW_ELEMS (64 * 64 * 64)              // mask fp32 [w][q 64][k 64], -1e30 pad
#define RH_ELEMS (12 * 64 * 64)              // rpb  fp32 [h][q 64][k 64], 0 pad
#define MW_OFF 0
#define RH_OFF (MW_ELEMS * 4)
#define WTQ_OFF (RH_OFF + RH_ELEMS * 4)
#define WTQ_ELEMS (1152 * 384)               // W_qkv^T bf16 [col][k]
#define BQ_OFF (WTQ_OFF + WTQ_ELEMS * 2)     // scaled qkv bias fp32 [1152]
#define WTP_OFF (BQ_OFF + 1152 * 4)          // W_proj^T bf16 [384][384]
#define WTP_ELEMS (384 * 384)

__global__ __launch_bounds__(256) void wa_prep(
    const float* __restrict__ mask, const float* __restrict__ qkv_w,
    const float* __restrict__ qkv_b, const float* __restrict__ rpb,
    const float* __restrict__ proj_w, unsigned char* __restrict__ ws)
{
    float* Mw = (float*)(ws + MW_OFF);
    float* Rh = (float*)(ws + RH_OFF);
    unsigned short* wtq = (unsigned short*)(ws + WTQ_OFF);
    float* bq = (float*)(ws + BQ_OFF);
    unsigned short* wtp = (unsigned short*)(ws + WTP_OFF);
    const int TOT = MW_ELEMS + RH_ELEMS + WTQ_ELEMS + 1152 + WTP_ELEMS;
    for (int idx = blockIdx.x * 256 + threadIdx.x; idx < TOT; idx += gridDim.x * 256) {
        if (idx < MW_ELEMS) {
            int m = idx & 63, n = (idx >> 6) & 63, w = idx >> 12;
            Mw[idx] = (n < NTOK && m < NTOK) ? mask[(w * NTOK + n) * NTOK + m] : -1e30f;
        } else if (idx < MW_ELEMS + RH_ELEMS) {
            int t = idx - MW_ELEMS;
            int m = t & 63, n = (t >> 6) & 63, h = t >> 12;
            float v = 0.f;
            if (n < NTOK && m < NTOK) {
                int ni = n / 7, nj = n % 7, mi = m / 7, mj = m % 7;
                int ridx = (ni - mi + 6) * 13 + (nj - mj + 6);
                v = rpb[ridx * 12 + h];
            }
            Rh[t] = v;
        } else if (idx < MW_ELEMS + RH_ELEMS + WTQ_ELEMS) {
            int t = idx - MW_ELEMS - RH_ELEMS;
            int j = t / 384, k = t - j * 384;
            float s = (j < 384) ? SCALE : 1.0f;
            wtq[t] = f2bf(qkv_w[k * 1152 + j] * s);
        } else if (idx < MW_ELEMS + RH_ELEMS + WTQ_ELEMS + 1152) {
            int j = idx - MW_ELEMS - RH_ELEMS - WTQ_ELEMS;
            bq[j] = qkv_b[j] * ((j < 384) ? SCALE : 1.0f);
        } else {
            int t = idx - MW_ELEMS - RH_ELEMS - WTQ_ELEMS - 1152;
            int j = t / 384, k = t - j * 384;
            wtp[t] = f2bf(proj_w[k * 384 + j]);
        }
    }
}

// R13: full 32x32x16 MFMA rewrite. The per-wave critical chain was ~700
// LDS-pipe ops (ds_read + ds_bpermute shuffles from 16x16 fragment repacks) at
// ~300cy each (R11/R12 falsified the VMEM theories). With 32x32 tiles, C/D ->
// frag conversion needs only lane<->lane^32 exchange: pre-select + 2 shfl_xor
// per 8-row block (fragcd), softmax reduce is lane-local + 1 shfl. LDS ops
// drop ~700 -> ~280/wave; MFMA instruction count halves. (256,3): no-spill.
__global__ __launch_bounds__(256, 3) void wa_main(
    const float* __restrict__ x, const float* __restrict__ bproj,
    const unsigned char* __restrict__ ws, float* __restrict__ out)
{
    __shared__ unsigned short X[49 * 396];

    const float* Mw = (const float*)(ws + MW_OFF);
    const float* Rh = (const float*)(ws + RH_OFF);
    const unsigned short* wtq = (const unsigned short*)(ws + WTQ_OFF);
    const float* bq = (const float*)(ws + BQ_OFF);
    const unsigned short* wtp = (const unsigned short*)(ws + WTP_OFF);

    const int tid = threadIdx.x;
    const int b = blockIdx.x;
    const int w64 = b & 63;
    const int wv = tid >> 6;
    const int lane = tid & 63;
    const int l31 = lane & 31;
    const int hl = lane >> 5;

    // ---- stage x (49 rows) as bf16, pitch 396 ----
    const float4* xw = (const float4*)(x + (size_t)b * (NTOK * 384));
    for (int i = tid; i < NTOK * 96; i += 256) {
        float4 v = xw[i];
        int row = i / 96, col = (i - row * 96) * 4;
        u16x4 o;
        o.x = f2bf(v.x); o.y = f2bf(v.y); o.z = f2bf(v.z); o.w = f2bf(v.w);
        *(u16x4*)&X[row * 396 + col] = o;
    }
    __syncthreads();

    // AO scratch: 2nd half of this block's own out slice (bf16 [head][token][32d])
    unsigned short* aow = (unsigned short*)(out + (size_t)b * 18816 + 9408);

    int xoff2[2];
    #pragma unroll
    for (int t = 0; t < 2; t++) {
        int tok = 32 * t + l31; if (tok > 48) tok = 48;
        xoff2[t] = tok * 396 + 8 * hl;
    }

    for (int hh = 0; hh < 3; hh++) {
        const int h = wv * 3 + hh;
        const unsigned short* wqp = wtq + (size_t)(h * 32 + l31) * 384 + 8 * hl;
        const unsigned short* wkp = wqp + (size_t)384 * 384;
        const unsigned short* wvp = wqp + (size_t)768 * 384;

        // ---- fused QKV: Q^T,K^T (D[d][tok]), V (D[tok][d]); K=384, 24 ksteps ----
        f32x16 qa[2], ka[2], va[2];
        {
            #pragma unroll
            for (int a = 0; a < 4; a++) {
                f32x4 bqv = *(const f32x4*)(bq + h * 32 + 8 * a + 4 * hl);
                f32x4 bkv = *(const f32x4*)(bq + 384 + h * 32 + 8 * a + 4 * hl);
                #pragma unroll
                for (int i = 0; i < 4; i++) {
                    qa[0][4 * a + i] = bqv[i]; qa[1][4 * a + i] = bqv[i];
                    ka[0][4 * a + i] = bkv[i]; ka[1][4 * a + i] = bkv[i];
                }
            }
            float bvv = bq[768 + h * 32 + l31];
            #pragma unroll
            for (int i = 0; i < 16; i++) { va[0][i] = bvv; va[1][i] = bvv; }
        }
        #pragma unroll
        for (int ks = 0; ks < 24; ks++) {
            short8 xb0 = *(const short8*)&X[xoff2[0] + ks * 16];
            short8 xb1 = *(const short8*)&X[xoff2[1] + ks * 16];
            short8 wq = *(const short8*)(wqp + ks * 16);
            short8 wk = *(const short8*)(wkp + ks * 16);
            short8 wvf = *(const short8*)(wvp + ks * 16);
            __builtin_amdgcn_s_setprio(1);
            qa[0] = MFMA32(wq, xb0, qa[0]);
            qa[1] = MFMA32(wq, xb1, qa[1]);
            ka[0] = MFMA32(wk, xb0, ka[0]);
            ka[1] = MFMA32(wk, xb1, ka[1]);
            va[0] = MFMA32(xb0, wvf, va[0]);
            va[1] = MFMA32(xb1, wvf, va[1]);
            __builtin_amdgcn_s_setprio(0);
        }

        // ---- convert to frags (VALU + 2 shfl_xor(32) per block) ----
        short8 qf[2][2], kf[2][2], vf[4];
        #pragma unroll
        for (int t = 0; t < 2; t++) {
            qf[t][0] = fragcd<0>(qa[t], hl); qf[t][1] = fragcd<1>(qa[t], hl);
            kf[t][0] = fragcd<0>(ka[t], hl); kf[t][1] = fragcd<1>(ka[t], hl);
        }
        vf[0] = fragcd<0>(va[0], hl); vf[1] = fragcd<1>(va[0], hl);
        vf[2] = fragcd<0>(va[1], hl); vf[3] = fragcd<1>(va[1], hl);

        // ---- S^T = K·Q^T : D[k-tok][q-tok], 2x2 tiles of 32x32, K=32 (2 steps) ----
        f32x16 S[2][2];
        {
            f32x16 z;
            #pragma unroll
            for (int i = 0; i < 16; i++) z[i] = 0.f;
            __builtin_amdgcn_s_setprio(1);
            #pragma unroll
            for (int kt = 0; kt < 2; kt++)
                #pragma unroll
                for (int qt = 0; qt < 2; qt++) {
                    S[kt][qt] = MFMA32(kf[kt][0], qf[qt][0], z);
                    S[kt][qt] = MFMA32(kf[kt][1], qf[qt][1], S[kt][qt]);
                }
            __builtin_amdgcn_s_setprio(0);
        }

        // ---- bias + softmax over k (lane-local 32 values + partner via 1 shfl) ----
        const float* mwp = Mw + (size_t)w64 * 4096;
        const float* rhp = Rh + (size_t)h * 4096;
        short8 pf[2][4];
        #pragma unroll
        for (int qt = 0; qt < 2; qt++) {
            const int q = 32 * qt + l31;
            #pragma unroll
            for (int kt = 0; kt < 2; kt++)
                #pragma unroll
                for (int a = 0; a < 4; a++) {
                    const int off = q * 64 + 32 * kt + 8 * a + 4 * hl;
                    f32x4 mv = *(const f32x4*)(mwp + off);
                    f32x4 rv4 = *(const f32x4*)(rhp + off);
                    #pragma unroll
                    for (int i = 0; i < 4; i++)
                        S[kt][qt][4 * a + i] += mv[i] + rv4[i];
                }
            float red[16];
            #pragma unroll
            for (int i = 0; i < 16; i++) red[i] = fmaxf(S[0][qt][i], S[1][qt][i]);
            #pragma unroll
            for (int s = 8; s > 0; s >>= 1)
                #pragma unroll
                for (int i = 0; i < s; i++) red[i] = fmaxf(red[i], red[i + s]);
            float mx = fmaxf(red[0], __shfl_xor(red[0], 32));
            #pragma unroll
            for (int i = 0; i < 16; i++) {
                float e0 = __expf(S[0][qt][i] - mx);
                float e1 = __expf(S[1][qt][i] - mx);
                S[0][qt][i] = e0; S[1][qt][i] = e1;
                red[i] = e0 + e1;
            }
            #pragma unroll
            for (int s = 8; s > 0; s >>= 1)
                #pragma unroll
                for (int i = 0; i < s; i++) red[i] += red[i + s];
            float sm = red[0] + __shfl_xor(red[0], 32);
            float rv = 1.0f / sm;
            #pragma unroll
            for (int i = 0; i < 16; i++) { S[0][qt][i] *= rv; S[1][qt][i] *= rv; }
            pf[qt][0] = fragcd<0>(S[0][qt], hl);
            pf[qt][1] = fragcd<1>(S[0][qt], hl);
            pf[qt][2] = fragcd<0>(S[1][qt], hl);
            pf[qt][3] = fragcd<1>(S[1][qt], hl);
        }

        // ---- O^T = V^T·P : D[d][q], 1x2 tiles, K=64 (4 steps) ----
        f32x16 OT[2];
        {
            f32x16 z;
            #pragma unroll
            for (int i = 0; i < 16; i++) z[i] = 0.f;
            __builtin_amdgcn_s_setprio(1);
            #pragma unroll
            for (int qt = 0; qt < 2; qt++) {
                OT[qt] = MFMA32(vf[0], pf[qt][0], z);
                OT[qt] = MFMA32(vf[1], pf[qt][1], OT[qt]);
                OT[qt] = MFMA32(vf[2], pf[qt][2], OT[qt]);
                OT[qt] = MFMA32(vf[3], pf[qt][3], OT[qt]);
            }
            __builtin_amdgcn_s_setprio(0);
        }

        // ---- store AO bf16 [head][token][32 d] ----
        #pragma unroll
        for (int qt = 0; qt < 2; qt++) {
            int token = 32 * qt + l31;
            if (token < NTOK) {
                #pragma unroll
                for (int a = 0; a < 4; a++) {
                    unsigned int lo = pkbf(OT[qt][4 * a + 0], OT[qt][4 * a + 1]);
                    unsigned int hi = pkbf(OT[qt][4 * a + 2], OT[qt][4 * a + 3]);
                    *(uint2*)(aow + (h * NTOK + token) * 32 + 8 * a + 4 * hl) = make_uint2(lo, hi);
                }
            }
        }
    }

    __threadfence_block();
    __syncthreads();

    // ---- proj: [49x384] @ Wt_proj + b; wave owns 96 cols (3 tiles of 32) ----
    {
        const int c0 = wv * 96;
        f32x16 pr[2][3];
        #pragma unroll
        for (int nt = 0; nt < 3; nt++) {
            float bv = bproj[c0 + 32 * nt + l31];
            #pragma unroll
            for (int i = 0; i < 16; i++) { pr[0][nt][i] = bv; pr[1][nt][i] = bv; }
        }
        const int t0 = l31;
        int t1 = 32 + l31; if (t1 > 48) t1 = 48;
        #pragma unroll
        for (int ks = 0; ks < 24; ks++) {
            const int head = ks >> 1;
            const int koff = 16 * (ks & 1) + 8 * hl;
            short8 a0 = *(const short8*)(aow + (head * NTOK + t0) * 32 + koff);
            short8 a1 = *(const short8*)(aow + (head * NTOK + t1) * 32 + koff);
            short8 bf[3];
            #pragma unroll
            for (int nt = 0; nt < 3; nt++)
                bf[nt] = *(const short8*)(wtp + (size_t)(c0 + 32 * nt + l31) * 384 + ks * 16 + 8 * hl);
            __builtin_amdgcn_s_setprio(1);
            #pragma unroll
            for (int nt = 0; nt < 3; nt++) {
                pr[0][nt] = MFMA32(a0, bf[nt], pr[0][nt]);
                pr[1][nt] = MFMA32(a1, bf[nt], pr[1][nt]);
            }
            __builtin_amdgcn_s_setprio(0);
        }
        __syncthreads();   // all AO reads complete before in-place fp32 stores
        float* outb = out + (size_t)b * 18816;
        #pragma unroll
        for (int mt = 0; mt < 2; mt++)
            #pragma unroll
            for (int nt = 0; nt < 3; nt++)
                #pragma unroll
                for (int a = 0; a < 4; a++)
                    #pragma unroll
                    for (int i = 0; i < 4; i++) {
                        int tok = 32 * mt + 8 * a + 4 * hl + i;
                        if (tok < NTOK)
                            outb[tok * 384 + c0 + 32 * nt + l31] = pr[mt][nt][4 * a + i];
                    }
    }
}

extern "C" void kernel_launch(void* const* d_in, const int* in_sizes, int n_in,
                              void* d_out, int out_size, void* d_ws, size_t ws_size,
                              hipStream_t stream) {
    const float* x      = (const float*)d_in[0];
    const float* mask   = (const float*)d_in[1];
    const float* qkv_w  = (const float*)d_in[2];
    const float* qkv_b  = (const float*)d_in[3];
    const float* rpb    = (const float*)d_in[4];
    const float* proj_w = (const float*)d_in[5];
    const float* proj_b = (const float*)d_in[6];
    unsigned char* ws = (unsigned char*)d_ws;

    wa_prep<<<dim3(1024), dim3(256), 0, stream>>>(mask, qkv_w, qkv_b, rpb, proj_w, ws);
    wa_main<<<dim3(NB), dim3(256), 0, stream>>>(x, proj_b, ws, (float*)d_out);
}

// Round 14
// 844.276 us; speedup vs baseline: 1.0367x; 1.0367x over previous
//
#include <hip/hip_runtime.h>
#include <hip/hip_bf16.h>

#define NTOK 49
#define NB 2048
#define SCALE 0.17677669529663687f  // 32^-0.5

typedef __attribute__((ext_vector_type(8))) short short8;
typedef __attribute__((ext_vector_type(4))) float f32x4;
typedef __attribute__((ext_vector_type(4))) unsigned short u16x4;

static __device__ __forceinline__ unsigned short f2bf(float f) {
    union { float f; unsigned int u; } v; v.f = f;
    unsigned int r = v.u + 0x7FFFu + ((v.u >> 16) & 1u);
    return (unsigned short)(r >> 16);
}

static __device__ __forceinline__ unsigned int pkbf(float lo, float hi) {
    __hip_bfloat162 h = __float22bfloat162_rn(make_float2(lo, hi));  // .x -> low16
    union { __hip_bfloat162 h; unsigned int u; } c; c.h = h; return c.u;
}

// g-axis repack: source C/D regs (row = 16*mt + 4*g' + r) -> frag (k-elem = 8*g + j).
static __device__ __forceinline__ short8 repack(const unsigned int* pkA, const unsigned int* pkB,
                                                int lid, int g) {
    int sA = lid + ((2 * (g & 1)) << 4);
    int sB = sA + 16;
    unsigned int l0 = __shfl((int)pkA[0], sA), h0 = __shfl((int)pkB[0], sA);
    unsigned int l1 = __shfl((int)pkA[1], sA), h1 = __shfl((int)pkB[1], sA);
    unsigned int l2 = __shfl((int)pkA[0], sB), h2 = __shfl((int)pkB[0], sB);
    unsigned int l3 = __shfl((int)pkA[1], sB), h3 = __shfl((int)pkB[1], sB);
    bool hi = (g & 2);
    union { short8 s; unsigned int u[4]; } r;
    r.u[0] = hi ? h0 : l0;
    r.u[1] = hi ? h1 : l1;
    r.u[2] = hi ? h2 : l2;
    r.u[3] = hi ? h3 : l3;
    return r.s;
}

// ---- workspace layout (bytes) ----
#define MW_ELEMS (64 * 64 * 64)              // mask fp32 [w][q 64][k 64], -1e30 pad
#define RH_ELEMS (12 * 64 * 64)              // rpb  fp32 [h][q 64][k 64], 0 pad
#define MW_OFF 0
#define RH_OFF (MW_ELEMS * 4)
#define WTQ_OFF (RH_OFF + RH_ELEMS * 4)
#define WTQ_ELEMS (1152 * 384)               // W_qkv^T bf16 [col][k]
#define BQ_OFF (WTQ_OFF + WTQ_ELEMS * 2)     // scaled qkv bias fp32 [1152]
#define WTP_OFF (BQ_OFF + 1152 * 4)          // W_proj^T bf16 [384][384]
#define WTP_ELEMS (384 * 384)

__global__ __launch_bounds__(256) void wa_prep(
    const float* __restrict__ mask, const float* __restrict__ qkv_w,
    const float* __restrict__ qkv_b, const float* __restrict__ rpb,
    const float* __restrict__ proj_w, unsigned char* __restrict__ ws)
{
    float* Mw = (float*)(ws + MW_OFF);
    float* Rh = (float*)(ws + RH_OFF);
    unsigned short* wtq = (unsigned short*)(ws + WTQ_OFF);
    float* bq = (float*)(ws + BQ_OFF);
    unsigned short* wtp = (unsigned short*)(ws + WTP_OFF);
    const int TOT = MW_ELEMS + RH_ELEMS + WTQ_ELEMS + 1152 + WTP_ELEMS;
    for (int idx = blockIdx.x * 256 + threadIdx.x; idx < TOT; idx += gridDim.x * 256) {
        if (idx < MW_ELEMS) {
            int m = idx & 63, n = (idx >> 6) & 63, w = idx >> 12;
            Mw[idx] = (n < NTOK && m < NTOK) ? mask[(w * NTOK + n) * NTOK + m] : -1e30f;
        } else if (idx < MW_ELEMS + RH_ELEMS) {
            int t = idx - MW_ELEMS;
            int m = t & 63, n = (t >> 6) & 63, h = t >> 12;
            float v = 0.f;
            if (n < NTOK && m < NTOK) {
                int ni = n / 7, nj = n % 7, mi = m / 7, mj = m % 7;
                int ridx = (ni - mi + 6) * 13 + (nj - mj + 6);
                v = rpb[ridx * 12 + h];
            }
            Rh[t] = v;
        } else if (idx < MW_ELEMS + RH_ELEMS + WTQ_ELEMS) {
            int t = idx - MW_ELEMS - RH_ELEMS;
            int j = t / 384, k = t - j * 384;
            float s = (j < 384) ? SCALE : 1.0f;
            wtq[t] = f2bf(qkv_w[k * 1152 + j] * s);
        } else if (idx < MW_ELEMS + RH_ELEMS + WTQ_ELEMS + 1152) {
            int j = idx - MW_ELEMS - RH_ELEMS - WTQ_ELEMS;
            bq[j] = qkv_b[j] * ((j < 384) ? SCALE : 1.0f);
        } else {
            int t = idx - MW_ELEMS - RH_ELEMS - WTQ_ELEMS - 1152;
            int j = t / 384, k = t - j * 384;
            wtp[t] = f2bf(proj_w[k * 384 + j]);
        }
    }
}

// Fused per-window kernel, 4 waves x 3 heads. LDS = X[49][396] bf16 only.
// R14 = R6 + FUSED QKV (R4's single 12-iter X-sweep computing Q^T,K^T,V
// together). R4-vs-R6 confound resolved: fused was only ever run at 2
// blocks/CU. Fused at (256,3) cuts X ds_reads 432->144/wave and gives each
// loop iter 24 MFMAs (~120cy) to hide its 10 loads (split passes had 8
// MFMAs/40cy) -- 3x the latency-hiding per chain link, no asm needed.
// Fused-phase reg peak ~151 <= (256,3) budget ~170 (only no-spill point).
__global__ __launch_bounds__(256, 3) void wa_main(
    const float* __restrict__ x, const float* __restrict__ bproj,
    const unsigned char* __restrict__ ws, float* __restrict__ out)
{
    __shared__ unsigned short X[49 * 396];

    const float* Mw = (const float*)(ws + MW_OFF);
    const float* Rh = (const float*)(ws + RH_OFF);
    const unsigned short* wtq = (const unsigned short*)(ws + WTQ_OFF);
    const float* bq = (const float*)(ws + BQ_OFF);
    const unsigned short* wtp = (const unsigned short*)(ws + WTP_OFF);

    const int tid = threadIdx.x;
    const int b = blockIdx.x;
    const int w64 = b & 63;
    const int wv = tid >> 6;
    const int lane = tid & 63;
    const int lid = lane & 15;
    const int g = lane >> 4;

    // ---- stage x (49 rows) as bf16, pitch 396 (conflict-free) ----
    const float4* xw = (const float4*)(x + (size_t)b * (NTOK * 384));
    for (int i = tid; i < NTOK * 96; i += 256) {
        float4 v = xw[i];
        int row = i / 96, col = (i - row * 96) * 4;
        u16x4 o;
        o.x = f2bf(v.x); o.y = f2bf(v.y); o.z = f2bf(v.z); o.w = f2bf(v.w);
        *(u16x4*)&X[row * 396 + col] = o;
    }
    __syncthreads();

    // AO scratch: 2nd half of this block's own out slice (bf16 [head][token][32d])
    unsigned short* aow = (unsigned short*)(out + (size_t)b * 18816 + 9408);

    int xoff[4];
    #pragma unroll
    for (int t = 0; t < 4; t++) {
        int row = 16 * t + lid; if (row > 48) row = 48;
        xoff[t] = row * 396 + g * 8;
    }

    for (int hh = 0; hh < 3; hh++) {
        const int h = wv * 3 + hh;
        const unsigned short* wqp = wtq + (size_t)(h * 32 + lid) * 384 + g * 8;
        const unsigned short* wkp = wtq + (size_t)(384 + h * 32 + lid) * 384 + g * 8;
        const unsigned short* wvp = wtq + (size_t)(768 + h * 32 + lid) * 384 + g * 8;

        // ---- FUSED QKV: Q^T,K^T (M=32 d, N=64 tok), V (M=64 tok, N=32 d);
        //      one X sweep, K=384 ----
        short8 qf[4], kf[4], vf[2][2];
        {
            f32x4 qa[2][4], ka[2][4], va[4][2];
            #pragma unroll
            for (int mt = 0; mt < 2; mt++) {
                f32x4 bqv = *(const f32x4*)(bq + h * 32 + 16 * mt + 4 * g);
                f32x4 bkv = *(const f32x4*)(bq + 384 + h * 32 + 16 * mt + 4 * g);
                #pragma unroll
                for (int nt = 0; nt < 4; nt++) { qa[mt][nt] = bqv; ka[mt][nt] = bkv; }
            }
            #pragma unroll
            for (int nt = 0; nt < 2; nt++) {
                float bv = bq[768 + h * 32 + 16 * nt + lid];
                #pragma unroll
                for (int mt = 0; mt < 4; mt++) va[mt][nt] = (f32x4){bv, bv, bv, bv};
            }
            for (int kk = 0; kk < 12; kk++) {
                short8 xb[4], wq[2], wk[2], wvf[2];
                #pragma unroll
                for (int t = 0; t < 4; t++) xb[t] = *(const short8*)&X[xoff[t] + kk * 32];
                #pragma unroll
                for (int mt = 0; mt < 2; mt++) {
                    wq[mt]  = *(const short8*)(wqp + (size_t)(16 * mt) * 384 + kk * 32);
                    wk[mt]  = *(const short8*)(wkp + (size_t)(16 * mt) * 384 + kk * 32);
                    wvf[mt] = *(const short8*)(wvp + (size_t)(16 * mt) * 384 + kk * 32);
                }
                __builtin_amdgcn_s_setprio(1);
                #pragma unroll
                for (int mt = 0; mt < 2; mt++)
                    #pragma unroll
                    for (int nt = 0; nt < 4; nt++) {
                        qa[mt][nt] = __builtin_amdgcn_mfma_f32_16x16x32_bf16(wq[mt], xb[nt], qa[mt][nt], 0, 0, 0);
                        ka[mt][nt] = __builtin_amdgcn_mfma_f32_16x16x32_bf16(wk[mt], xb[nt], ka[mt][nt], 0, 0, 0);
                    }
                #pragma unroll
                for (int mt = 0; mt < 4; mt++)
                    #pragma unroll
                    for (int nt = 0; nt < 2; nt++)
                        va[mt][nt] = __builtin_amdgcn_mfma_f32_16x16x32_bf16(xb[mt], wvf[nt], va[mt][nt], 0, 0, 0);
                __builtin_amdgcn_s_setprio(0);
            }
            #pragma unroll
            for (int nt = 0; nt < 4; nt++) {
                unsigned int q0[2] = { pkbf(qa[0][nt][0], qa[0][nt][1]), pkbf(qa[0][nt][2], qa[0][nt][3]) };
                unsigned int q1[2] = { pkbf(qa[1][nt][0], qa[1][nt][1]), pkbf(qa[1][nt][2], qa[1][nt][3]) };
                qf[nt] = repack(q0, q1, lid, g);
                unsigned int k0[2] = { pkbf(ka[0][nt][0], ka[0][nt][1]), pkbf(ka[0][nt][2], ka[0][nt][3]) };
                unsigned int k1[2] = { pkbf(ka[1][nt][0], ka[1][nt][1]), pkbf(ka[1][nt][2], ka[1][nt][3]) };
                kf[nt] = repack(k0, k1, lid, g);
            }
            #pragma unroll
            for (int nt = 0; nt < 2; nt++) {
                unsigned int pv[4][2];
                #pragma unroll
                for (int mt = 0; mt < 4; mt++) {
                    pv[mt][0] = pkbf(va[mt][nt][0], va[mt][nt][1]);
                    pv[mt][1] = pkbf(va[mt][nt][2], va[mt][nt][3]);
                }
                vf[0][nt] = repack(pv[0], pv[1], lid, g);
                vf[1][nt] = repack(pv[2], pv[3], lid, g);
            }
        }

        // ---- S^T = K·Q^T : D[k-tok][q-tok]  (16 MFMA, K=32) ----
        f32x4 S[4][4];  // [kt][qt]
        __builtin_amdgcn_s_setprio(1);
        #pragma unroll
        for (int kt = 0; kt < 4; kt++)
            #pragma unroll
            for (int qt = 0; qt < 4; qt++)
                S[kt][qt] = __builtin_amdgcn_mfma_f32_16x16x32_bf16(kf[kt], qf[qt], (f32x4){0.f, 0.f, 0.f, 0.f}, 0, 0, 0);
        __builtin_amdgcn_s_setprio(0);

        // ---- bias (mask + rpb, L2-resident) + softmax over k; normalize -> pf ----
        const float* mwp = Mw + (size_t)w64 * 4096;
        const float* rhp = Rh + (size_t)h * 4096;
        short8 pf[4][2];
        #pragma unroll
        for (int qt = 0; qt < 4; qt++) {
            #pragma unroll
            for (int kt = 0; kt < 4; kt++) {
                int off = (16 * qt + lid) * 64 + 16 * kt + 4 * g;
                S[kt][qt] += *(const f32x4*)(mwp + off) + *(const f32x4*)(rhp + off);
            }
            float mx = S[0][qt][0];
            #pragma unroll
            for (int kt = 0; kt < 4; kt++)
                #pragma unroll
                for (int r = 0; r < 4; r++) mx = fmaxf(mx, S[kt][qt][r]);
            mx = fmaxf(mx, __shfl_xor(mx, 16));
            mx = fmaxf(mx, __shfl_xor(mx, 32));
            float sm = 0.f;
            #pragma unroll
            for (int kt = 0; kt < 4; kt++)
                #pragma unroll
                for (int r = 0; r < 4; r++) {
                    float e = __expf(S[kt][qt][r] - mx);
                    S[kt][qt][r] = e; sm += e;
                }
            sm += __shfl_xor(sm, 16);
            sm += __shfl_xor(sm, 32);
            float rv = 1.0f / sm;
            unsigned int pp[4][2];
            #pragma unroll
            for (int kt = 0; kt < 4; kt++) {
                pp[kt][0] = pkbf(S[kt][qt][0] * rv, S[kt][qt][1] * rv);
                pp[kt][1] = pkbf(S[kt][qt][2] * rv, S[kt][qt][3] * rv);
            }
            pf[qt][0] = repack(pp[0], pp[1], lid, g);
            pf[qt][1] = repack(pp[2], pp[3], lid, g);
        }

        // ---- O^T = V^T·P^T : D[d][q-tok]  (operand-swapped PV) ----
        f32x4 OT[2][4];  // [dt][qt]: col = q-token = lid, row = d = 16dt+4g+r
        #pragma unroll
        for (int dt = 0; dt < 2; dt++)
            #pragma unroll
            for (int qt = 0; qt < 4; qt++) OT[dt][qt] = (f32x4){0.f,0.f,0.f,0.f};
        __builtin_amdgcn_s_setprio(1);
        #pragma unroll
        for (int kb = 0; kb < 2; kb++)
            #pragma unroll
            for (int dt = 0; dt < 2; dt++)
                #pragma unroll
                for (int qt = 0; qt < 4; qt++)
                    OT[dt][qt] = __builtin_amdgcn_mfma_f32_16x16x32_bf16(vf[kb][dt], pf[qt][kb], OT[dt][qt], 0, 0, 0);
        __builtin_amdgcn_s_setprio(0);

        // ---- store AO bf16 [head][token][32 d]: 8B per lane, contiguous full lines ----
        #pragma unroll
        for (int qt = 0; qt < 4; qt++) {
            int token = 16 * qt + lid;
            if (token < NTOK) {
                #pragma unroll
                for (int dt = 0; dt < 2; dt++) {
                    unsigned int lo = pkbf(OT[dt][qt][0], OT[dt][qt][1]);
                    unsigned int hi = pkbf(OT[dt][qt][2], OT[dt][qt][3]);
                    *(uint2*)(aow + (h * NTOK + token) * 32 + 16 * dt + 4 * g) = make_uint2(lo, hi);
                }
            }
        }
    }

    __threadfence_block();
    __syncthreads();

    // ---- proj: [49x384] @ Wt_proj + b; wave owns 96 cols; A-frags from AO scratch ----
    {
        const int c0 = wv * 96;
        f32x4 acc[4][6];
        #pragma unroll
        for (int nt = 0; nt < 6; nt++) {
            float bv = bproj[c0 + nt * 16 + lid];
            #pragma unroll
            for (int mt = 0; mt < 4; mt++) acc[mt][nt] = (f32x4){bv, bv, bv, bv};
        }
        #pragma unroll
        for (int kk = 0; kk < 12; kk++) {   // kk == head index; k = kk*32 + g*8 ..
            short8 a[4], bf[6];
            #pragma unroll
            for (int mt = 0; mt < 4; mt++) {
                int row = lid + 16 * mt;
                if (row > 48) row = 48;
                a[mt] = *(const short8*)(aow + (kk * NTOK + row) * 32 + g * 8);
            }
            #pragma unroll
            for (int nt = 0; nt < 6; nt++)
                bf[nt] = *(const short8*)(wtp + (size_t)(c0 + nt * 16 + lid) * 384 + kk * 32 + g * 8);
            __builtin_amdgcn_s_setprio(1);
            #pragma unroll
            for (int mt = 0; mt < 4; mt++)
                #pragma unroll
                for (int nt = 0; nt < 6; nt++)
                    acc[mt][nt] = __builtin_amdgcn_mfma_f32_16x16x32_bf16(a[mt], bf[nt], acc[mt][nt], 0, 0, 0);
            __builtin_amdgcn_s_setprio(0);
        }
        __syncthreads();   // all AO reads complete before in-place fp32 stores
        float* outb = out + (size_t)b * 18816;
        #pragma unroll
        for (int mt = 0; mt < 4; mt++)
            #pragma unroll
            for (int nt = 0; nt < 6; nt++)
                #pragma unroll
                for (int r = 0; r < 4; r++) {
                    int n = g * 4 + r + 16 * mt;
                    if (n < NTOK)
                        outb[n * 384 + c0 + nt * 16 + lid] = acc[mt][nt][r];
                }
    }
}

extern "C" void kernel_launch(void* const* d_in, const int* in_sizes, int n_in,
                              void* d_out, int out_size, void* d_ws, size_t ws_size,
                              hipStream_t stream) {
    const float* x      = (const float*)d_in[0];
    const float* mask   = (const float*)d_in[1];
    const float* qkv_w  = (const float*)d_in[2];
    const float* qkv_b  = (const float*)d_in[3];
    const float* rpb    = (const float*)d_in[4];
    const float* proj_w = (const float*)d_in[5];
    const float* proj_b = (const float*)d_in[6];
    unsigned char* ws = (unsigned char*)d_ws;

    wa_prep<<<dim3(1024), dim3(256), 0, stream>>>(mask, qkv_w, qkv_b, rpb, proj_w, ws);
    wa_main<<<dim3(NB), dim3(256), 0, stream>>>(x, proj_b, ws, (float*)d_out);
}